// Round 3
// baseline (216.451 us; speedup 1.0000x reference)
//
#include <hip/hip_runtime.h>
#include <cstdint>

#define DIM   768
#define HEADS 12
#define HDIM  64
#define BATCH 4
#define SEQ   2048
#define MROWS (BATCH*SEQ)   // 8192

typedef __bf16 bf16;
typedef __bf16 bf16x4_t __attribute__((ext_vector_type(4)));
typedef __bf16 bf16x8_t __attribute__((ext_vector_type(8)));
typedef float  f32x4_t  __attribute__((ext_vector_type(4)));
typedef float  f32x16_t __attribute__((ext_vector_type(16)));
typedef unsigned int u32x4_t __attribute__((ext_vector_type(4)));
typedef unsigned int u32x2_t __attribute__((ext_vector_type(2)));

// ---------------- fp32 -> bf16 casts ----------------
__global__ void cast_bf16_kernel(const float* __restrict__ src, bf16* __restrict__ dst, int n4) {
    int i = blockIdx.x * blockDim.x + threadIdx.x;
    if (i >= n4) return;
    const float4 v = reinterpret_cast<const float4*>(src)[i];
    bf16x4_t o;
    o[0] = (bf16)v.x; o[1] = (bf16)v.y; o[2] = (bf16)v.z; o[3] = (bf16)v.w;
    reinterpret_cast<bf16x4_t*>(dst)[i] = o;
}

__global__ void cast_w4_kernel(const float* __restrict__ s0, const float* __restrict__ s1,
                               const float* __restrict__ s2, const float* __restrict__ s3,
                               bf16* __restrict__ d0, bf16* __restrict__ d1,
                               bf16* __restrict__ d2, bf16* __restrict__ d3, int n4) {
    int i = blockIdx.x * blockDim.x + threadIdx.x;
    if (i >= n4) return;
    int y = blockIdx.y;
    const float* src = (y == 0) ? s0 : (y == 1) ? s1 : (y == 2) ? s2 : s3;
    bf16* dst        = (y == 0) ? d0 : (y == 1) ? d1 : (y == 2) ? d2 : d3;
    const float4 v = reinterpret_cast<const float4*>(src)[i];
    bf16x4_t o;
    o[0] = (bf16)v.x; o[1] = (bf16)v.y; o[2] = (bf16)v.z; o[3] = (bf16)v.w;
    reinterpret_cast<bf16x4_t*>(dst)[i] = o;
}

// async global->LDS, 16B per lane. LDS dest is wave-uniform base + lane*16.
__device__ __forceinline__ void gload_lds16(const bf16* g, bf16* l) {
    __builtin_amdgcn_global_load_lds((const __attribute__((address_space(1))) void*)g,
                                     (__attribute__((address_space(3))) void*)l, 16, 0, 0);
}

// ---------------- merged projection GEMM v2 ----------------
// All slices: A = W{q,k,v} (M=dfull), B = X (N=sample) -> C[dfull][sample].
// BK=64, XOR chunk swizzle (2-way = free), 128x128 tile.
// z=0 -> Q [B,H,N,64] (pre-scaled by log2(e)/8), packed bf16x4 stores
// z=1 -> K [B,H,N,64], packed bf16x4 stores
// z=2 -> Vt [768][8192] row-major, epilogue via LDS for coalesced b128 stores
__global__ __launch_bounds__(256, 3) void qkvv_gemm(
        const bf16* __restrict__ X,
        const bf16* __restrict__ Wq, const bf16* __restrict__ Wk, const bf16* __restrict__ Wv,
        bf16* __restrict__ Q, bf16* __restrict__ Kd, bf16* __restrict__ Vt)
{
    __shared__ __align__(16) bf16 SM[128 * 128];   // As (16KB) + Bs (16KB); reused as C-tile for z=2
    bf16* As = SM;               // W rows (dfull), swizzled
    bf16* Bs = SM + 128 * 64;    // X rows (sample), swizzled
    const int tid  = threadIdx.x;
    const int z    = blockIdx.z;
    const bf16* Ap = (z == 0) ? Wq : (z == 1 ? Wk : Wv);
    const int m0   = blockIdx.x * 128;   // dfull
    const int n0   = blockIdx.y * 128;   // sample
    const int lane = tid & 63;
    const int w    = tid >> 6;
    const int wm   = (w & 1) * 64, wn = (w >> 1) * 64;
    const int lr   = lane & 15, quad = lane >> 4;

    f32x4_t acc[4][4] = {};

    for (int kk = 0; kk < DIM; kk += 64) {
        #pragma unroll
        for (int i = 0; i < 4; ++i) {
            int c = tid + i * 256;              // 0..1023
            int row = c >> 3, ch = c & 7;
            int gch = ch ^ (row & 7);
            gload_lds16(Ap + (size_t)(m0 + row) * DIM + kk + gch * 8, &As[row * 64 + ch * 8]);
            gload_lds16(X  + (size_t)(n0 + row) * DIM + kk + gch * 8, &Bs[row * 64 + ch * 8]);
        }
        __syncthreads();
        #pragma unroll
        for (int ks = 0; ks < 2; ++ks) {
            bf16x8_t af[4], bfr[4];
            #pragma unroll
            for (int i = 0; i < 4; ++i) {
                int row = wm + i * 16 + lr;
                int ch = (ks * 4 + quad) ^ (row & 7);
                af[i] = *reinterpret_cast<const bf16x8_t*>(&As[row * 64 + ch * 8]);
            }
            #pragma unroll
            for (int j = 0; j < 4; ++j) {
                int row = wn + j * 16 + lr;
                int ch = (ks * 4 + quad) ^ (row & 7);
                bfr[j] = *reinterpret_cast<const bf16x8_t*>(&Bs[row * 64 + ch * 8]);
            }
            #pragma unroll
            for (int i = 0; i < 4; ++i)
                #pragma unroll
                for (int j = 0; j < 4; ++j)
                    acc[i][j] = __builtin_amdgcn_mfma_f32_16x16x32_bf16(af[i], bfr[j], acc[i][j], 0, 0, 0);
        }
        __syncthreads();
    }

    if (z == 2) {
        // Stage C-tile (128x128 bf16 = 32KB, exactly As+Bs) in LDS, then store
        // full 256B rows of Vt[dfull][sample] with b128 per lane (was: 64 scalar
        // 2B stores per lane into 32B segments).
        #pragma unroll
        for (int i = 0; i < 4; ++i) {
            int ml = wm + i * 16 + quad * 4;
            #pragma unroll
            for (int j = 0; j < 4; ++j) {
                int nl = wn + j * 16 + lr;
                #pragma unroll
                for (int r = 0; r < 4; ++r)
                    SM[(ml + r) * 128 + nl] = (bf16)acc[i][j][r];
            }
        }
        __syncthreads();
        const int rr = tid >> 4, cc = tid & 15;   // 16 rows x 16 chunks per round
        #pragma unroll
        for (int rnd = 0; rnd < 8; ++rnd) {
            int ml = rnd * 16 + rr;
            *reinterpret_cast<bf16x8_t*>(&Vt[(size_t)(m0 + ml) * MROWS + n0 + cc * 8]) =
                *reinterpret_cast<const bf16x8_t*>(&SM[ml * 128 + cc * 8]);
        }
    } else {
        // lane's 4 regs = 4 consecutive dfull -> packed bf16x4 store
        const float sc = (z == 0) ? 0.18033688011112042f : 1.0f;   // log2(e)/8 into Q
        bf16* dst = (z == 0) ? Q : Kd;
        #pragma unroll
        for (int i = 0; i < 4; ++i) {
            int mb = m0 + wm + i * 16 + quad * 4;   // dfull base, mult of 4
            int h  = mb >> 6, d0 = mb & 63;
            #pragma unroll
            for (int j = 0; j < 4; ++j) {
                int sample = n0 + wn + j * 16 + lr;
                int b = sample >> 11, srow = sample & 2047;
                bf16x4_t o;
                #pragma unroll
                for (int r = 0; r < 4; ++r)
                    o[r] = (bf16)(acc[i][j][r] * sc);
                *reinterpret_cast<bf16x4_t*>(
                    &dst[(((size_t)b * HEADS + h) * SEQ + srow) * HDIM + d0]) = o;
            }
        }
    }
}

// ---------------- output projection GEMM (+bias, fp32 out) ----------------
// 64x128 tile, BK=64, swizzled. grid (6,128)=768 blocks = 3-4/CU balanced.
__global__ __launch_bounds__(256, 4) void out_gemm(
        const bf16* __restrict__ A,       // [8192,768]
        const bf16* __restrict__ W,       // [768,768]
        const float* __restrict__ bias,
        float* __restrict__ out)          // [8192,768] f32
{
    __shared__ __align__(16) bf16 As[64*64];
    __shared__ __align__(16) bf16 Bs[128*64];
    const int tid  = threadIdx.x;
    const int n0   = blockIdx.x * 128;
    const int m0   = blockIdx.y * 64;
    const int lane = tid & 63;
    const int w    = tid >> 6;
    const int wm   = (w & 1) * 32, wn = (w >> 1) * 64;
    const int lr   = lane & 15, quad = lane >> 4;

    f32x4_t acc[2][4] = {};

    for (int kk = 0; kk < DIM; kk += 64) {
        #pragma unroll
        for (int i = 0; i < 2; ++i) {           // As: 64x64 = 512 chunks
            int c = tid + i * 256;
            int row = c >> 3, ch = c & 7;
            int gch = ch ^ (row & 7);
            gload_lds16(A + (size_t)(m0 + row) * DIM + kk + gch * 8, &As[row * 64 + ch * 8]);
        }
        #pragma unroll
        for (int i = 0; i < 4; ++i) {           // Bs: 128x64 = 1024 chunks
            int c = tid + i * 256;
            int row = c >> 3, ch = c & 7;
            int gch = ch ^ (row & 7);
            gload_lds16(W + (size_t)(n0 + row) * DIM + kk + gch * 8, &Bs[row * 64 + ch * 8]);
        }
        __syncthreads();
        #pragma unroll
        for (int ks = 0; ks < 2; ++ks) {
            bf16x8_t af[2], bfr[4];
            #pragma unroll
            for (int i = 0; i < 2; ++i) {
                int row = wm + i * 16 + lr;
                int ch = (ks * 4 + quad) ^ (row & 7);
                af[i] = *reinterpret_cast<const bf16x8_t*>(&As[row * 64 + ch * 8]);
            }
            #pragma unroll
            for (int j = 0; j < 4; ++j) {
                int row = wn + j * 16 + lr;
                int ch = (ks * 4 + quad) ^ (row & 7);
                bfr[j] = *reinterpret_cast<const bf16x8_t*>(&Bs[row * 64 + ch * 8]);
            }
            #pragma unroll
            for (int i = 0; i < 2; ++i)
                #pragma unroll
                for (int j = 0; j < 4; ++j)
                    acc[i][j] = __builtin_amdgcn_mfma_f32_16x16x32_bf16(af[i], bfr[j], acc[i][j], 0, 0, 0);
        }
        __syncthreads();
    }

    #pragma unroll
    for (int i = 0; i < 2; ++i) {
        int mbase = m0 + wm + i * 16 + quad * 4;
        #pragma unroll
        for (int j = 0; j < 4; ++j) {
            int n = n0 + wn + j * 16 + lr;
            float bv = bias[n];
            #pragma unroll
            for (int r = 0; r < 4; ++r) {
                int m = mbase + r;
                out[(size_t)m * DIM + n] = acc[i][j][r] + bv;
            }
        }
    }
}

// ---------------- flash attention v8: VALU row-sum (no ones-MFMA) ----------------
// v7 spent 4 of 20 MFMA/iter multiplying P by a ones-vector to get softmax
// denominators (20% of matrix work). v8: each lane's 32 sacc values are all 32
// keys (of this 64-key tile) for its own q = lane&31, so the denominator partial
// is a register tree-sum of the f32 exp values (overlaps the bf16 pack on VALU).
// End of kernel: one cross-half shfl-add + 16 shfls redistribute totals into the
// C-layout that the epilogue needs. Remaining SQ_LDS_BANK_CONFLICT (~6.3M) is
// structural ds_read_b128 overhead (12 cyc/read, m134) - not swizzle-fixable.
__global__ __launch_bounds__(256, 3) void attn_kernel(
        const bf16* __restrict__ Q, const bf16* __restrict__ Kd,
        const bf16* __restrict__ Vt, bf16* __restrict__ Ab)
{
    __shared__ __align__(16) bf16 KV[2][2][64*64];   // [buf][K|V][row*64] swizzled

    const int tid  = threadIdx.x;
    const int bh   = blockIdx.y;
    const int b    = bh / HEADS, h = bh % HEADS;
    const int q0   = blockIdx.x * 128;
    const int lane = tid & 63, w = tid >> 6;
    const int l31  = lane & 31, hw = lane >> 5;
    const int wq   = w * 32;

    const size_t qkbase = (size_t)bh * SEQ * HDIM;
    const size_t vbase  = (size_t)h * HDIM * MROWS + (size_t)b * SEQ;

    const int src_row = tid >> 3, src_ch = tid & 7;
    const int src_gch = src_ch ^ (src_row & 7);
    const int src_row2 = (tid + 256) >> 3, src_ch2 = tid & 7;
    const int src_gch2 = src_ch2 ^ (src_row2 & 7);

    {
        bf16* Qst = &KV[1][0][0];
        #pragma unroll
        for (int i = 0; i < 4; ++i) {
            int c = tid + i * 256;
            int row = c >> 3, ch = c & 7;
            int gch = ch ^ (row & 7);
            gload_lds16(Q + qkbase + (size_t)(q0 + row) * HDIM + gch * 8, &Qst[row * 64 + ch * 8]);
        }
    }

    const bf16* kp1 = Kd + qkbase + (size_t)src_row  * HDIM + src_gch  * 8;
    const bf16* kp2 = Kd + qkbase + (size_t)src_row2 * HDIM + src_gch2 * 8;
    const bf16* vp1 = Vt + vbase  + (size_t)src_row  * MROWS + src_gch  * 8;
    const bf16* vp2 = Vt + vbase  + (size_t)src_row2 * MROWS + src_gch2 * 8;
    bf16* kl1 = &KV[0][0][src_row  * 64 + src_ch  * 8];
    bf16* kl2 = &KV[0][0][src_row2 * 64 + src_ch2 * 8];
    bf16* vl1 = &KV[0][1][src_row  * 64 + src_ch  * 8];
    bf16* vl2 = &KV[0][1][src_row2 * 64 + src_ch2 * 8];
    const ptrdiff_t kstep = 64 * HDIM, vstep = 64;
    const ptrdiff_t lstep = 2 * 64 * 64;

    gload_lds16(kp1, kl1); gload_lds16(kp2, kl2);
    gload_lds16(vp1, vl1); gload_lds16(vp2, vl2);
    __syncthreads();

    bf16x8_t qf[4];
    {
        const bf16* Qst = &KV[1][0][0];
        int row = wq + l31;
        #pragma unroll
        for (int g = 0; g < 4; ++g) {
            int ch = (2 * g + hw) ^ (row & 7);
            qf[g] = *reinterpret_cast<const bf16x8_t*>(&Qst[row * 64 + ch * 8]);
        }
    }
    __syncthreads();

    f32x16_t oacc[2] = {};
    float rs = 0.0f;   // softmax denominator partial for q = l31 (this lane's 32 keys/tile)

    for (int it = 0; it < SEQ / 64; ++it) {
        const int buf = it & 1;
        if (it + 1 < SEQ / 64) {
            const ptrdiff_t g = (ptrdiff_t)(it + 1);
            const ptrdiff_t l = (buf ^ 1) ? lstep : 0;
            gload_lds16(kp1 + g * kstep, kl1 + l); gload_lds16(kp2 + g * kstep, kl2 + l);
            gload_lds16(vp1 + g * vstep, vl1 + l); gload_lds16(vp2 + g * vstep, vl2 + l);
        }

        const bf16* Ks = &KV[buf][0][0];
        const bf16* Vs = &KV[buf][1][0];

        f32x16_t sacc[2] = {};
        #pragma unroll
        for (int kc = 0; kc < 2; ++kc) {
            int row = kc * 32 + l31;
            #pragma unroll
            for (int g = 0; g < 4; ++g) {
                int ch = (2 * g + hw) ^ (row & 7);
                bf16x8_t af = *reinterpret_cast<const bf16x8_t*>(&Ks[row * 64 + ch * 8]);
                sacc[kc] = __builtin_amdgcn_mfma_f32_32x32x16_bf16(af, qf[g], sacc[kc], 0, 0, 0);
            }
        }

        bf16x8_t pk[4];
        #pragma unroll
        for (int kg = 0; kg < 4; ++kg) {
            float e[8];
            #pragma unroll
            for (int j = 0; j < 8; ++j) {
                e[j] = __builtin_amdgcn_exp2f(sacc[kg >> 1][(kg & 1) * 8 + j]);
                pk[kg][j] = (bf16)e[j];
            }
            rs += ((e[0] + e[1]) + (e[2] + e[3])) + ((e[4] + e[5]) + (e[6] + e[7]));
        }

        #pragma unroll
        for (int dc = 0; dc < 2; ++dc) {
            int row = dc * 32 + l31;
            #pragma unroll
            for (int kg = 0; kg < 4; ++kg) {
                // lane(hw=0) reads full chunk (2kg)^swz, lane(hw=1) reads (2kg+1)^swz.
                // permlane32_swap(a,b) -> { {a.lo, b.lo}, {a.hi, b.hi} } across the
                // lane<32 / lane>=32 split:
                //   hw=0 ends with cols {16kg+0..3, 16kg+8..11}
                //   hw=1 ends with cols {16kg+4..7, 16kg+12..15}
                // == the original b64 pair layout (matches pk's formal-k mapping).
                int myc = (2 * kg + hw) ^ (row & 7);
                union { u32x4_t i; bf16x8_t v; } u;
                u.i = *reinterpret_cast<const u32x4_t*>(&Vs[row * 64 + myc * 8]);
                u32x2_t r02 = __builtin_amdgcn_permlane32_swap(u.i[0], u.i[2], false, false);
                u32x2_t r13 = __builtin_amdgcn_permlane32_swap(u.i[1], u.i[3], false, false);
                u.i[0] = r02[0]; u.i[2] = r02[1];
                u.i[1] = r13[0]; u.i[3] = r13[1];
                oacc[dc] = __builtin_amdgcn_mfma_f32_32x32x16_bf16(pk[kg], u.v, oacc[dc], 0, 0, 0);
            }
        }
        __syncthreads();
    }

    // Combine the two key-halves (lane q,hw=0 holds keys {0-3,8-11,...}, hw=1 the
    // rest), then redistribute per-q totals into the epilogue's C-layout.
    rs += __shfl(rs, lane ^ 32, 64);
    float inv[16];
    #pragma unroll
    for (int r = 0; r < 16; ++r) {
        int srcq = (r & 3) + 8 * (r >> 2) + 4 * hw;      // q_rel of oacc row r
        inv[r] = 1.0f / __shfl(rs, srcq, 64);            // lane srcq holds total(q_rel=srcq)
    }
    #pragma unroll
    for (int dc = 0; dc < 2; ++dc) {
        int d = dc * 32 + l31;
        #pragma unroll
        for (int r = 0; r < 16; ++r) {
            int q = q0 + wq + (r & 3) + 8 * (r >> 2) + 4 * hw;
            Ab[((size_t)b * SEQ + q) * DIM + h * HDIM + d] = (bf16)(oacc[dc][r] * inv[r]);
        }
    }
}

extern "C" void kernel_launch(void* const* d_in, const int* in_sizes, int n_in,
                              void* d_out, int out_size, void* d_ws, size_t ws_size,
                              hipStream_t stream) {
    (void)in_sizes; (void)n_in; (void)out_size; (void)ws_size;
    const float* x  = (const float*)d_in[0];
    const float* Wq = (const float*)d_in[1];
    const float* Wk = (const float*)d_in[2];
    const float* Wv = (const float*)d_in[3];
    const float* Wp = (const float*)d_in[4];
    const float* bp = (const float*)d_in[5];
    float* out = (float*)d_out;

    char* ws = (char*)d_ws;
    size_t off = 0;
    auto alloc = [&](size_t bytes) {
        void* p = ws + off;
        off += (bytes + 255) & ~(size_t)255;
        return p;
    };
    const size_t big = (size_t)MROWS * DIM * sizeof(bf16);
    const size_t wsz = (size_t)DIM * DIM * sizeof(bf16);
    bf16* Xb  = (bf16*)alloc(big);
    bf16* Qb  = (bf16*)alloc(big);
    bf16* Kb  = (bf16*)alloc(big);
    bf16* Vtb = (bf16*)alloc(big);
    bf16* Wqb = (bf16*)alloc(wsz);
    bf16* Wkb = (bf16*)alloc(wsz);
    bf16* Wvb = (bf16*)alloc(wsz);
    bf16* Wpb = (bf16*)alloc(wsz);
    bf16* Ab  = Xb;   // Xb dead after projections

    const int x4 = MROWS * DIM / 4;
    cast_bf16_kernel<<<(x4 + 255) / 256, 256, 0, stream>>>(x, Xb, x4);
    const int w4 = DIM * DIM / 4;
    cast_w4_kernel<<<dim3((w4 + 255) / 256, 4), 256, 0, stream>>>(
        Wq, Wk, Wv, Wp, Wqb, Wkb, Wvb, Wpb, w4);

    qkvv_gemm<<<dim3(DIM / 128, MROWS / 128, 3), 256, 0, stream>>>(
        Xb, Wqb, Wkb, Wvb, Qb, Kb, Vtb);

    attn_kernel<<<dim3(SEQ / 128, BATCH * HEADS), 256, 0, stream>>>(Qb, Kb, Vtb, Ab);

    out_gemm<<<dim3(DIM / 128, MROWS / 64), 256, 0, stream>>>(Ab, Wpb, bp, out);
}

// Round 4
// 206.276 us; speedup vs baseline: 1.0493x; 1.0493x over previous
//
#include <hip/hip_runtime.h>
#include <cstdint>

#define DIM   768
#define HEADS 12
#define HDIM  64
#define BATCH 4
#define SEQ   2048
#define MROWS (BATCH*SEQ)   // 8192

typedef __bf16 bf16;
typedef __bf16 bf16x4_t __attribute__((ext_vector_type(4)));
typedef __bf16 bf16x8_t __attribute__((ext_vector_type(8)));
typedef float  f32x4_t  __attribute__((ext_vector_type(4)));
typedef float  f32x16_t __attribute__((ext_vector_type(16)));
typedef unsigned int u32x4_t __attribute__((ext_vector_type(4)));
typedef unsigned int u32x2_t __attribute__((ext_vector_type(2)));

// ---------------- fp32 -> bf16 casts ----------------
__global__ void cast_bf16_kernel(const float* __restrict__ src, bf16* __restrict__ dst, int n4) {
    int i = blockIdx.x * blockDim.x + threadIdx.x;
    if (i >= n4) return;
    const float4 v = reinterpret_cast<const float4*>(src)[i];
    bf16x4_t o;
    o[0] = (bf16)v.x; o[1] = (bf16)v.y; o[2] = (bf16)v.z; o[3] = (bf16)v.w;
    reinterpret_cast<bf16x4_t*>(dst)[i] = o;
}

__global__ void cast_w4_kernel(const float* __restrict__ s0, const float* __restrict__ s1,
                               const float* __restrict__ s2, const float* __restrict__ s3,
                               bf16* __restrict__ d0, bf16* __restrict__ d1,
                               bf16* __restrict__ d2, bf16* __restrict__ d3, int n4) {
    int i = blockIdx.x * blockDim.x + threadIdx.x;
    if (i >= n4) return;
    int y = blockIdx.y;
    const float* src = (y == 0) ? s0 : (y == 1) ? s1 : (y == 2) ? s2 : s3;
    bf16* dst        = (y == 0) ? d0 : (y == 1) ? d1 : (y == 2) ? d2 : d3;
    const float4 v = reinterpret_cast<const float4*>(src)[i];
    bf16x4_t o;
    o[0] = (bf16)v.x; o[1] = (bf16)v.y; o[2] = (bf16)v.z; o[3] = (bf16)v.w;
    reinterpret_cast<bf16x4_t*>(dst)[i] = o;
}

// async global->LDS, 16B per lane. LDS dest is wave-uniform base + lane*16.
__device__ __forceinline__ void gload_lds16(const bf16* g, bf16* l) {
    __builtin_amdgcn_global_load_lds((const __attribute__((address_space(1))) void*)g,
                                     (__attribute__((address_space(3))) void*)l, 16, 0, 0);
}

// ---------------- merged projection GEMM v3: + XCD-chunked swizzle ----------------
// All slices: A = W{q,k,v} (M=dfull), B = X (N=sample) -> C[dfull][sample].
// BK=64, XOR chunk swizzle (2-way = free), 128x128 tile.
// Block swizzle: 1152 blocks = 8 XCDs x 144; each XCD gets a contiguous chunk of
// the (z,y)-major logical order so its per-k working set (~0.5 MB) is L2-resident
// (was: same-X-tile blocks scattered across XCDs -> 453 MB of L3 re-reads).
__global__ __launch_bounds__(256, 3) void qkvv_gemm(
        const bf16* __restrict__ X,
        const bf16* __restrict__ Wq, const bf16* __restrict__ Wk, const bf16* __restrict__ Wv,
        bf16* __restrict__ Q, bf16* __restrict__ Kd, bf16* __restrict__ Vt)
{
    __shared__ __align__(16) bf16 SM[128 * 128];   // As (16KB) + Bs (16KB); reused as C-tile for z=2
    bf16* As = SM;               // W rows (dfull), swizzled
    bf16* Bs = SM + 128 * 64;    // X rows (sample), swizzled
    const int tid  = threadIdx.x;

    // XCD-chunked bijective remap (nwg=1152, 1152%8==0, chunk=144)
    const int d  = blockIdx.x + 6 * blockIdx.y + 384 * blockIdx.z;
    const int L  = (d & 7) * 144 + (d >> 3);
    const int z  = L / 384;
    const int rem = L % 384;
    const int m0 = (rem % 6) * 128;   // dfull
    const int n0 = (rem / 6) * 128;   // sample

    const bf16* Ap = (z == 0) ? Wq : (z == 1 ? Wk : Wv);
    const int lane = tid & 63;
    const int w    = tid >> 6;
    const int wm   = (w & 1) * 64, wn = (w >> 1) * 64;
    const int lr   = lane & 15, quad = lane >> 4;

    f32x4_t acc[4][4] = {};

    for (int kk = 0; kk < DIM; kk += 64) {
        #pragma unroll
        for (int i = 0; i < 4; ++i) {
            int c = tid + i * 256;              // 0..1023
            int row = c >> 3, ch = c & 7;
            int gch = ch ^ (row & 7);
            gload_lds16(Ap + (size_t)(m0 + row) * DIM + kk + gch * 8, &As[row * 64 + ch * 8]);
            gload_lds16(X  + (size_t)(n0 + row) * DIM + kk + gch * 8, &Bs[row * 64 + ch * 8]);
        }
        __syncthreads();
        #pragma unroll
        for (int ks = 0; ks < 2; ++ks) {
            bf16x8_t af[4], bfr[4];
            #pragma unroll
            for (int i = 0; i < 4; ++i) {
                int row = wm + i * 16 + lr;
                int ch = (ks * 4 + quad) ^ (row & 7);
                af[i] = *reinterpret_cast<const bf16x8_t*>(&As[row * 64 + ch * 8]);
            }
            #pragma unroll
            for (int j = 0; j < 4; ++j) {
                int row = wn + j * 16 + lr;
                int ch = (ks * 4 + quad) ^ (row & 7);
                bfr[j] = *reinterpret_cast<const bf16x8_t*>(&Bs[row * 64 + ch * 8]);
            }
            #pragma unroll
            for (int i = 0; i < 4; ++i)
                #pragma unroll
                for (int j = 0; j < 4; ++j)
                    acc[i][j] = __builtin_amdgcn_mfma_f32_16x16x32_bf16(af[i], bfr[j], acc[i][j], 0, 0, 0);
        }
        __syncthreads();
    }

    if (z == 2) {
        // Stage C-tile (128x128 bf16 = 32KB, exactly As+Bs) in LDS, then store
        // full 256B rows of Vt[dfull][sample] with b128 per lane.
        #pragma unroll
        for (int i = 0; i < 4; ++i) {
            int ml = wm + i * 16 + quad * 4;
            #pragma unroll
            for (int j = 0; j < 4; ++j) {
                int nl = wn + j * 16 + lr;
                #pragma unroll
                for (int r = 0; r < 4; ++r)
                    SM[(ml + r) * 128 + nl] = (bf16)acc[i][j][r];
            }
        }
        __syncthreads();
        const int rr = tid >> 4, cc = tid & 15;   // 16 rows x 16 chunks per round
        #pragma unroll
        for (int rnd = 0; rnd < 8; ++rnd) {
            int ml = rnd * 16 + rr;
            *reinterpret_cast<bf16x8_t*>(&Vt[(size_t)(m0 + ml) * MROWS + n0 + cc * 8]) =
                *reinterpret_cast<const bf16x8_t*>(&SM[ml * 128 + cc * 8]);
        }
    } else {
        // lane's 4 regs = 4 consecutive dfull -> packed bf16x4 store
        const float sc = (z == 0) ? 0.18033688011112042f : 1.0f;   // log2(e)/8 into Q
        bf16* dst = (z == 0) ? Q : Kd;
        #pragma unroll
        for (int i = 0; i < 4; ++i) {
            int mb = m0 + wm + i * 16 + quad * 4;   // dfull base, mult of 4
            int h  = mb >> 6, d0 = mb & 63;
            #pragma unroll
            for (int j = 0; j < 4; ++j) {
                int sample = n0 + wn + j * 16 + lr;
                int b = sample >> 11, srow = sample & 2047;
                bf16x4_t o;
                #pragma unroll
                for (int r = 0; r < 4; ++r)
                    o[r] = (bf16)(acc[i][j][r] * sc);
                *reinterpret_cast<bf16x4_t*>(
                    &dst[(((size_t)b * HEADS + h) * SEQ + srow) * HDIM + d0]) = o;
            }
        }
    }
}

// ---------------- output projection GEMM (+bias, fp32 out) ----------------
// 64x128 tile, BK=64, swizzled LDS + XCD-chunked block swizzle (768 = 8 x 96):
// each XCD's 16 m-tiles + full W column-slice stream through its own L2.
__global__ __launch_bounds__(256, 4) void out_gemm(
        const bf16* __restrict__ A,       // [8192,768]
        const bf16* __restrict__ W,       // [768,768]
        const float* __restrict__ bias,
        float* __restrict__ out)          // [8192,768] f32
{
    __shared__ __align__(16) bf16 As[64*64];
    __shared__ __align__(16) bf16 Bs[128*64];
    const int tid  = threadIdx.x;

    const int d  = blockIdx.x + 6 * blockIdx.y;   // 0..767
    const int L  = (d & 7) * 96 + (d >> 3);
    const int n0 = (L % 6) * 128;
    const int m0 = (L / 6) * 64;

    const int lane = tid & 63;
    const int w    = tid >> 6;
    const int wm   = (w & 1) * 32, wn = (w >> 1) * 64;
    const int lr   = lane & 15, quad = lane >> 4;

    f32x4_t acc[2][4] = {};

    for (int kk = 0; kk < DIM; kk += 64) {
        #pragma unroll
        for (int i = 0; i < 2; ++i) {           // As: 64x64 = 512 chunks
            int c = tid + i * 256;
            int row = c >> 3, ch = c & 7;
            int gch = ch ^ (row & 7);
            gload_lds16(A + (size_t)(m0 + row) * DIM + kk + gch * 8, &As[row * 64 + ch * 8]);
        }
        #pragma unroll
        for (int i = 0; i < 4; ++i) {           // Bs: 128x64 = 1024 chunks
            int c = tid + i * 256;
            int row = c >> 3, ch = c & 7;
            int gch = ch ^ (row & 7);
            gload_lds16(W + (size_t)(n0 + row) * DIM + kk + gch * 8, &Bs[row * 64 + ch * 8]);
        }
        __syncthreads();
        #pragma unroll
        for (int ks = 0; ks < 2; ++ks) {
            bf16x8_t af[2], bfr[4];
            #pragma unroll
            for (int i = 0; i < 2; ++i) {
                int row = wm + i * 16 + lr;
                int ch = (ks * 4 + quad) ^ (row & 7);
                af[i] = *reinterpret_cast<const bf16x8_t*>(&As[row * 64 + ch * 8]);
            }
            #pragma unroll
            for (int j = 0; j < 4; ++j) {
                int row = wn + j * 16 + lr;
                int ch = (ks * 4 + quad) ^ (row & 7);
                bfr[j] = *reinterpret_cast<const bf16x8_t*>(&Bs[row * 64 + ch * 8]);
            }
            #pragma unroll
            for (int i = 0; i < 2; ++i)
                #pragma unroll
                for (int j = 0; j < 4; ++j)
                    acc[i][j] = __builtin_amdgcn_mfma_f32_16x16x32_bf16(af[i], bfr[j], acc[i][j], 0, 0, 0);
        }
        __syncthreads();
    }

    #pragma unroll
    for (int i = 0; i < 2; ++i) {
        int mbase = m0 + wm + i * 16 + quad * 4;
        #pragma unroll
        for (int j = 0; j < 4; ++j) {
            int n = n0 + wn + j * 16 + lr;
            float bv = bias[n];
            #pragma unroll
            for (int r = 0; r < 4; ++r) {
                int m = mbase + r;
                out[(size_t)m * DIM + n] = acc[i][j][r] + bv;
            }
        }
    }
}

// ---------------- flash attention v9: v7 + XCD swizzle + setprio ----------------
// v8's VALU row-sum REVERTED (it regressed: rsacc MFMAs were free overlap, VALU
// was the busy pipe). v9 = v7 (65.6us) plus:
//  - T1 XCD-chunked block swizzle: all 16 q-blocks of a bh (plus 6 bh) on one
//    XCD -> 3 MB of K/V L2-resident (FETCH was 104 MB from cross-XCD re-reads).
//  - T5 s_setprio(1) around MFMA clusters: 3 independent blocks/CU give the CU
//    scheduler phase diversity to arbitrate (m191: +4-7% attn).
// Remaining SQ_LDS_BANK_CONFLICT (~6.3M) is structural ds_read_b128 overhead.
__global__ __launch_bounds__(256, 3) void attn_kernel(
        const bf16* __restrict__ Q, const bf16* __restrict__ Kd,
        const bf16* __restrict__ Vt, bf16* __restrict__ Ab)
{
    __shared__ __align__(16) bf16 KV[2][2][64*64];   // [buf][K|V][row*64] swizzled

    const int tid  = threadIdx.x;

    // XCD-chunked bijective remap (nwg=768, chunk=96): bh major -> same-bh
    // q-blocks co-resident on one XCD.
    const int dd = blockIdx.x + 16 * blockIdx.y;   // 0..767
    const int L  = (dd & 7) * 96 + (dd >> 3);
    const int bh = L >> 4;
    const int q0 = (L & 15) * 128;

    const int b    = bh / HEADS, h = bh % HEADS;
    const int lane = tid & 63, w = tid >> 6;
    const int l31  = lane & 31, hw = lane >> 5;
    const int wq   = w * 32;

    const size_t qkbase = (size_t)bh * SEQ * HDIM;
    const size_t vbase  = (size_t)h * HDIM * MROWS + (size_t)b * SEQ;

    const int src_row = tid >> 3, src_ch = tid & 7;
    const int src_gch = src_ch ^ (src_row & 7);
    const int src_row2 = (tid + 256) >> 3, src_ch2 = tid & 7;
    const int src_gch2 = src_ch2 ^ (src_row2 & 7);

    {
        bf16* Qst = &KV[1][0][0];
        #pragma unroll
        for (int i = 0; i < 4; ++i) {
            int c = tid + i * 256;
            int row = c >> 3, ch = c & 7;
            int gch = ch ^ (row & 7);
            gload_lds16(Q + qkbase + (size_t)(q0 + row) * HDIM + gch * 8, &Qst[row * 64 + ch * 8]);
        }
    }

    const bf16* kp1 = Kd + qkbase + (size_t)src_row  * HDIM + src_gch  * 8;
    const bf16* kp2 = Kd + qkbase + (size_t)src_row2 * HDIM + src_gch2 * 8;
    const bf16* vp1 = Vt + vbase  + (size_t)src_row  * MROWS + src_gch  * 8;
    const bf16* vp2 = Vt + vbase  + (size_t)src_row2 * MROWS + src_gch2 * 8;
    bf16* kl1 = &KV[0][0][src_row  * 64 + src_ch  * 8];
    bf16* kl2 = &KV[0][0][src_row2 * 64 + src_ch2 * 8];
    bf16* vl1 = &KV[0][1][src_row  * 64 + src_ch  * 8];
    bf16* vl2 = &KV[0][1][src_row2 * 64 + src_ch2 * 8];
    const ptrdiff_t kstep = 64 * HDIM, vstep = 64;
    const ptrdiff_t lstep = 2 * 64 * 64;

    gload_lds16(kp1, kl1); gload_lds16(kp2, kl2);
    gload_lds16(vp1, vl1); gload_lds16(vp2, vl2);
    __syncthreads();

    bf16x8_t qf[4];
    {
        const bf16* Qst = &KV[1][0][0];
        int row = wq + l31;
        #pragma unroll
        for (int g = 0; g < 4; ++g) {
            int ch = (2 * g + hw) ^ (row & 7);
            qf[g] = *reinterpret_cast<const bf16x8_t*>(&Qst[row * 64 + ch * 8]);
        }
    }
    __syncthreads();

    f32x16_t oacc[2] = {};
    f32x16_t rsacc  = {};
    bf16x8_t ones8;
    #pragma unroll
    for (int i = 0; i < 8; ++i) ones8[i] = (bf16)1.0f;

    for (int it = 0; it < SEQ / 64; ++it) {
        const int buf = it & 1;
        if (it + 1 < SEQ / 64) {
            const ptrdiff_t g = (ptrdiff_t)(it + 1);
            const ptrdiff_t l = (buf ^ 1) ? lstep : 0;
            gload_lds16(kp1 + g * kstep, kl1 + l); gload_lds16(kp2 + g * kstep, kl2 + l);
            gload_lds16(vp1 + g * vstep, vl1 + l); gload_lds16(vp2 + g * vstep, vl2 + l);
        }

        const bf16* Ks = &KV[buf][0][0];
        const bf16* Vs = &KV[buf][1][0];

        f32x16_t sacc[2] = {};
        __builtin_amdgcn_s_setprio(1);
        #pragma unroll
        for (int kc = 0; kc < 2; ++kc) {
            int row = kc * 32 + l31;
            #pragma unroll
            for (int g = 0; g < 4; ++g) {
                int ch = (2 * g + hw) ^ (row & 7);
                bf16x8_t af = *reinterpret_cast<const bf16x8_t*>(&Ks[row * 64 + ch * 8]);
                sacc[kc] = __builtin_amdgcn_mfma_f32_32x32x16_bf16(af, qf[g], sacc[kc], 0, 0, 0);
            }
        }
        __builtin_amdgcn_s_setprio(0);

        bf16x8_t pk[4];
        #pragma unroll
        for (int kg = 0; kg < 4; ++kg) {
            #pragma unroll
            for (int j = 0; j < 8; ++j)
                pk[kg][j] = (bf16)__builtin_amdgcn_exp2f(sacc[kg >> 1][(kg & 1) * 8 + j]);
        }

        __builtin_amdgcn_s_setprio(1);
        #pragma unroll
        for (int kg = 0; kg < 4; ++kg)
            rsacc = __builtin_amdgcn_mfma_f32_32x32x16_bf16(pk[kg], ones8, rsacc, 0, 0, 0);

        #pragma unroll
        for (int dc = 0; dc < 2; ++dc) {
            int row = dc * 32 + l31;
            #pragma unroll
            for (int kg = 0; kg < 4; ++kg) {
                // lane(hw=0) reads full chunk (2kg)^swz, lane(hw=1) reads (2kg+1)^swz.
                // permlane32_swap(a,b) -> { {a.lo, b.lo}, {a.hi, b.hi} } across the
                // lane<32 / lane>=32 split:
                //   hw=0 ends with cols {16kg+0..3, 16kg+8..11}
                //   hw=1 ends with cols {16kg+4..7, 16kg+12..15}
                // == the original b64 pair layout (matches pk's formal-k mapping).
                int myc = (2 * kg + hw) ^ (row & 7);
                union { u32x4_t i; bf16x8_t v; } u;
                u.i = *reinterpret_cast<const u32x4_t*>(&Vs[row * 64 + myc * 8]);
                u32x2_t r02 = __builtin_amdgcn_permlane32_swap(u.i[0], u.i[2], false, false);
                u32x2_t r13 = __builtin_amdgcn_permlane32_swap(u.i[1], u.i[3], false, false);
                u.i[0] = r02[0]; u.i[2] = r02[1];
                u.i[1] = r13[0]; u.i[3] = r13[1];
                oacc[dc] = __builtin_amdgcn_mfma_f32_32x32x16_bf16(pk[kg], u.v, oacc[dc], 0, 0, 0);
            }
        }
        __builtin_amdgcn_s_setprio(0);
        __syncthreads();
    }

    float inv[16];
    #pragma unroll
    for (int r = 0; r < 16; ++r)
        inv[r] = 1.0f / rsacc[r];
    #pragma unroll
    for (int dc = 0; dc < 2; ++dc) {
        int d = dc * 32 + l31;
        #pragma unroll
        for (int r = 0; r < 16; ++r) {
            int q = q0 + wq + (r & 3) + 8 * (r >> 2) + 4 * hw;
            Ab[((size_t)b * SEQ + q) * DIM + h * HDIM + d] = (bf16)(oacc[dc][r] * inv[r]);
        }
    }
}

extern "C" void kernel_launch(void* const* d_in, const int* in_sizes, int n_in,
                              void* d_out, int out_size, void* d_ws, size_t ws_size,
                              hipStream_t stream) {
    (void)in_sizes; (void)n_in; (void)out_size; (void)ws_size;
    const float* x  = (const float*)d_in[0];
    const float* Wq = (const float*)d_in[1];
    const float* Wk = (const float*)d_in[2];
    const float* Wv = (const float*)d_in[3];
    const float* Wp = (const float*)d_in[4];
    const float* bp = (const float*)d_in[5];
    float* out = (float*)d_out;

    char* ws = (char*)d_ws;
    size_t off = 0;
    auto alloc = [&](size_t bytes) {
        void* p = ws + off;
        off += (bytes + 255) & ~(size_t)255;
        return p;
    };
    const size_t big = (size_t)MROWS * DIM * sizeof(bf16);
    const size_t wsz = (size_t)DIM * DIM * sizeof(bf16);
    bf16* Xb  = (bf16*)alloc(big);
    bf16* Qb  = (bf16*)alloc(big);
    bf16* Kb  = (bf16*)alloc(big);
    bf16* Vtb = (bf16*)alloc(big);
    bf16* Wqb = (bf16*)alloc(wsz);
    bf16* Wkb = (bf16*)alloc(wsz);
    bf16* Wvb = (bf16*)alloc(wsz);
    bf16* Wpb = (bf16*)alloc(wsz);
    bf16* Ab  = Xb;   // Xb dead after projections

    const int x4 = MROWS * DIM / 4;
    cast_bf16_kernel<<<(x4 + 255) / 256, 256, 0, stream>>>(x, Xb, x4);
    const int w4 = DIM * DIM / 4;
    cast_w4_kernel<<<dim3((w4 + 255) / 256, 4), 256, 0, stream>>>(
        Wq, Wk, Wv, Wp, Wqb, Wkb, Wvb, Wpb, w4);

    qkvv_gemm<<<dim3(DIM / 128, MROWS / 128, 3), 256, 0, stream>>>(
        Xb, Wqb, Wkb, Wvb, Qb, Kb, Vtb);

    attn_kernel<<<dim3(SEQ / 128, BATCH * HEADS), 256, 0, stream>>>(Qb, Kb, Vtb, Ab);

    out_gemm<<<dim3(DIM / 128, MROWS / 64), 256, 0, stream>>>(Ab, Wpb, bp, out);
}

// Round 5
// 206.167 us; speedup vs baseline: 1.0499x; 1.0005x over previous
//
#include <hip/hip_runtime.h>
#include <cstdint>

#define DIM   768
#define HEADS 12
#define HDIM  64
#define BATCH 4
#define SEQ   2048
#define MROWS (BATCH*SEQ)   // 8192

typedef __bf16 bf16;
typedef __bf16 bf16x4_t __attribute__((ext_vector_type(4)));
typedef __bf16 bf16x8_t __attribute__((ext_vector_type(8)));
typedef float  f32x4_t  __attribute__((ext_vector_type(4)));
typedef float  f32x16_t __attribute__((ext_vector_type(16)));

// ---------------- fp32 -> bf16 casts ----------------
__global__ void cast_bf16_kernel(const float* __restrict__ src, bf16* __restrict__ dst, int n4) {
    int i = blockIdx.x * blockDim.x + threadIdx.x;
    if (i >= n4) return;
    const float4 v = reinterpret_cast<const float4*>(src)[i];
    bf16x4_t o;
    o[0] = (bf16)v.x; o[1] = (bf16)v.y; o[2] = (bf16)v.z; o[3] = (bf16)v.w;
    reinterpret_cast<bf16x4_t*>(dst)[i] = o;
}

__global__ void cast_w4_kernel(const float* __restrict__ s0, const float* __restrict__ s1,
                               const float* __restrict__ s2, const float* __restrict__ s3,
                               bf16* __restrict__ d0, bf16* __restrict__ d1,
                               bf16* __restrict__ d2, bf16* __restrict__ d3, int n4) {
    int i = blockIdx.x * blockDim.x + threadIdx.x;
    if (i >= n4) return;
    int y = blockIdx.y;
    const float* src = (y == 0) ? s0 : (y == 1) ? s1 : (y == 2) ? s2 : s3;
    bf16* dst        = (y == 0) ? d0 : (y == 1) ? d1 : (y == 2) ? d2 : d3;
    const float4 v = reinterpret_cast<const float4*>(src)[i];
    bf16x4_t o;
    o[0] = (bf16)v.x; o[1] = (bf16)v.y; o[2] = (bf16)v.z; o[3] = (bf16)v.w;
    reinterpret_cast<bf16x4_t*>(dst)[i] = o;
}

// async global->LDS, 16B per lane. LDS dest is wave-uniform base + lane*16.
__device__ __forceinline__ void gload_lds16(const bf16* g, bf16* l) {
    __builtin_amdgcn_global_load_lds((const __attribute__((address_space(1))) void*)g,
                                     (__attribute__((address_space(3))) void*)l, 16, 0, 0);
}

// ---------------- merged projection GEMM v3: + XCD-chunked swizzle ----------------
// z=0 -> Q [B,H,N,64] (pre-scaled by log2(e)/8); z=1 -> K; z=2 -> Vt [768][8192]
// with each 16-sample group stored in piece order {0,2,1,3} (4-sample pieces) so
// attn's V b128 reads deliver MFMA B-fragments directly (no permlane fix-up).
__global__ __launch_bounds__(256, 3) void qkvv_gemm(
        const bf16* __restrict__ X,
        const bf16* __restrict__ Wq, const bf16* __restrict__ Wk, const bf16* __restrict__ Wv,
        bf16* __restrict__ Q, bf16* __restrict__ Kd, bf16* __restrict__ Vt)
{
    __shared__ __align__(16) bf16 SM[128 * 128];   // As (16KB) + Bs (16KB); reused as C-tile for z=2
    bf16* As = SM;               // W rows (dfull), swizzled
    bf16* Bs = SM + 128 * 64;    // X rows (sample), swizzled
    const int tid  = threadIdx.x;

    // XCD-chunked bijective remap (nwg=1152, 1152%8==0, chunk=144)
    const int d  = blockIdx.x + 6 * blockIdx.y + 384 * blockIdx.z;
    const int L  = (d & 7) * 144 + (d >> 3);
    const int z  = L / 384;
    const int rem = L % 384;
    const int m0 = (rem % 6) * 128;   // dfull
    const int n0 = (rem / 6) * 128;   // sample

    const bf16* Ap = (z == 0) ? Wq : (z == 1 ? Wk : Wv);
    const int lane = tid & 63;
    const int w    = tid >> 6;
    const int wm   = (w & 1) * 64, wn = (w >> 1) * 64;
    const int lr   = lane & 15, quad = lane >> 4;

    f32x4_t acc[4][4] = {};

    for (int kk = 0; kk < DIM; kk += 64) {
        #pragma unroll
        for (int i = 0; i < 4; ++i) {
            int c = tid + i * 256;              // 0..1023
            int row = c >> 3, ch = c & 7;
            int gch = ch ^ (row & 7);
            gload_lds16(Ap + (size_t)(m0 + row) * DIM + kk + gch * 8, &As[row * 64 + ch * 8]);
            gload_lds16(X  + (size_t)(n0 + row) * DIM + kk + gch * 8, &Bs[row * 64 + ch * 8]);
        }
        __syncthreads();
        #pragma unroll
        for (int ks = 0; ks < 2; ++ks) {
            bf16x8_t af[4], bfr[4];
            #pragma unroll
            for (int i = 0; i < 4; ++i) {
                int row = wm + i * 16 + lr;
                int ch = (ks * 4 + quad) ^ (row & 7);
                af[i] = *reinterpret_cast<const bf16x8_t*>(&As[row * 64 + ch * 8]);
            }
            #pragma unroll
            for (int j = 0; j < 4; ++j) {
                int row = wn + j * 16 + lr;
                int ch = (ks * 4 + quad) ^ (row & 7);
                bfr[j] = *reinterpret_cast<const bf16x8_t*>(&Bs[row * 64 + ch * 8]);
            }
            #pragma unroll
            for (int i = 0; i < 4; ++i)
                #pragma unroll
                for (int j = 0; j < 4; ++j)
                    acc[i][j] = __builtin_amdgcn_mfma_f32_16x16x32_bf16(af[i], bfr[j], acc[i][j], 0, 0, 0);
        }
        __syncthreads();
    }

    if (z == 2) {
        // Stage C-tile in LDS (with the 4-sample-piece involution 0,2,1,3 applied
        // within each 16-sample group), then store full 256B rows with b128.
        #pragma unroll
        for (int i = 0; i < 4; ++i) {
            int ml = wm + i * 16 + quad * 4;
            #pragma unroll
            for (int j = 0; j < 4; ++j) {
                int p   = lr >> 2;                               // piece 0..3
                int pp  = ((p & 1) << 1) | (p >> 1);             // 0,2,1,3
                int nl  = wn + j * 16 + (pp << 2) + (lr & 3);    // permuted sample
                #pragma unroll
                for (int r = 0; r < 4; ++r)
                    SM[(ml + r) * 128 + nl] = (bf16)acc[i][j][r];
            }
        }
        __syncthreads();
        const int rr = tid >> 4, cc = tid & 15;   // 16 rows x 16 chunks per round
        #pragma unroll
        for (int rnd = 0; rnd < 8; ++rnd) {
            int ml = rnd * 16 + rr;
            *reinterpret_cast<bf16x8_t*>(&Vt[(size_t)(m0 + ml) * MROWS + n0 + cc * 8]) =
                *reinterpret_cast<const bf16x8_t*>(&SM[ml * 128 + cc * 8]);
        }
    } else {
        // lane's 4 regs = 4 consecutive dfull -> packed bf16x4 store
        const float sc = (z == 0) ? 0.18033688011112042f : 1.0f;   // log2(e)/8 into Q
        bf16* dst = (z == 0) ? Q : Kd;
        #pragma unroll
        for (int i = 0; i < 4; ++i) {
            int mb = m0 + wm + i * 16 + quad * 4;   // dfull base, mult of 4
            int h  = mb >> 6, d0 = mb & 63;
            #pragma unroll
            for (int j = 0; j < 4; ++j) {
                int sample = n0 + wn + j * 16 + lr;
                int b = sample >> 11, srow = sample & 2047;
                bf16x4_t o;
                #pragma unroll
                for (int r = 0; r < 4; ++r)
                    o[r] = (bf16)(acc[i][j][r] * sc);
                *reinterpret_cast<bf16x4_t*>(
                    &dst[(((size_t)b * HEADS + h) * SEQ + srow) * HDIM + d0]) = o;
            }
        }
    }
}

// ---------------- output projection GEMM (+bias, fp32 out) ----------------
__global__ __launch_bounds__(256, 4) void out_gemm(
        const bf16* __restrict__ A,       // [8192,768]
        const bf16* __restrict__ W,       // [768,768]
        const float* __restrict__ bias,
        float* __restrict__ out)          // [8192,768] f32
{
    __shared__ __align__(16) bf16 As[64*64];
    __shared__ __align__(16) bf16 Bs[128*64];
    const int tid  = threadIdx.x;

    const int d  = blockIdx.x + 6 * blockIdx.y;   // 0..767
    const int L  = (d & 7) * 96 + (d >> 3);
    const int n0 = (L % 6) * 128;
    const int m0 = (L / 6) * 64;

    const int lane = tid & 63;
    const int w    = tid >> 6;
    const int wm   = (w & 1) * 32, wn = (w >> 1) * 64;
    const int lr   = lane & 15, quad = lane >> 4;

    f32x4_t acc[2][4] = {};

    for (int kk = 0; kk < DIM; kk += 64) {
        #pragma unroll
        for (int i = 0; i < 2; ++i) {           // As: 64x64 = 512 chunks
            int c = tid + i * 256;
            int row = c >> 3, ch = c & 7;
            int gch = ch ^ (row & 7);
            gload_lds16(A + (size_t)(m0 + row) * DIM + kk + gch * 8, &As[row * 64 + ch * 8]);
        }
        #pragma unroll
        for (int i = 0; i < 4; ++i) {           // Bs: 128x64 = 1024 chunks
            int c = tid + i * 256;
            int row = c >> 3, ch = c & 7;
            int gch = ch ^ (row & 7);
            gload_lds16(W + (size_t)(n0 + row) * DIM + kk + gch * 8, &Bs[row * 64 + ch * 8]);
        }
        __syncthreads();
        #pragma unroll
        for (int ks = 0; ks < 2; ++ks) {
            bf16x8_t af[2], bfr[4];
            #pragma unroll
            for (int i = 0; i < 2; ++i) {
                int row = wm + i * 16 + lr;
                int ch = (ks * 4 + quad) ^ (row & 7);
                af[i] = *reinterpret_cast<const bf16x8_t*>(&As[row * 64 + ch * 8]);
            }
            #pragma unroll
            for (int j = 0; j < 4; ++j) {
                int row = wn + j * 16 + lr;
                int ch = (ks * 4 + quad) ^ (row & 7);
                bfr[j] = *reinterpret_cast<const bf16x8_t*>(&Bs[row * 64 + ch * 8]);
            }
            #pragma unroll
            for (int i = 0; i < 2; ++i)
                #pragma unroll
                for (int j = 0; j < 4; ++j)
                    acc[i][j] = __builtin_amdgcn_mfma_f32_16x16x32_bf16(af[i], bfr[j], acc[i][j], 0, 0, 0);
        }
        __syncthreads();
    }

    #pragma unroll
    for (int i = 0; i < 2; ++i) {
        int mbase = m0 + wm + i * 16 + quad * 4;
        #pragma unroll
        for (int j = 0; j < 4; ++j) {
            int n = n0 + wn + j * 16 + lr;
            float bv = bias[n];
            #pragma unroll
            for (int r = 0; r < 4; ++r) {
                int m = mbase + r;
                out[(size_t)m * DIM + n] = acc[i][j][r] + bv;
            }
        }
    }
}

// ---------------- flash attention v10: lagged-PV pipeline + direct V frags ----------------
// v9 showed MFMA 41% + VALU 45% ~= the whole runtime: the per-wave serial chain
// QK->exp->PV never overlaps pipes. v10 (T15): iter t computes QK(t) then
// PV(t-1)+rsacc(t-1) as ONE 20-MFMA setprio cluster, then exp(t) as a pure
// VALU/trans cluster -> other waves' exp fills this wave's MFMA phase.
// V is triple-buffered (write t+1, idle t, read t-1: never collide; every buffer
// read was sealed by a barrier 2 iters earlier). K stays double-buffered.
// V fragments now read DIRECTLY as b128 (Vt pre-permuted in qkvv) - permlanes gone.
__global__ __launch_bounds__(256, 3) void attn_kernel(
        const bf16* __restrict__ Q, const bf16* __restrict__ Kd,
        const bf16* __restrict__ Vt, bf16* __restrict__ Ab)
{
    __shared__ __align__(16) bf16 SH[5 * 64 * 64];   // K dbuf (2x8KB) + V tribuf (3x8KB)
    bf16* Kb = SH;
    bf16* Vb = SH + 2 * 4096;

    const int tid  = threadIdx.x;

    // XCD-chunked bijective remap (nwg=768, chunk=96)
    const int dd = blockIdx.x + 16 * blockIdx.y;   // 0..767
    const int L  = (dd & 7) * 96 + (dd >> 3);
    const int bh = L >> 4;
    const int q0 = (L & 15) * 128;

    const int b    = bh / HEADS, h = bh % HEADS;
    const int lane = tid & 63, w = tid >> 6;
    const int l31  = lane & 31, hw = lane >> 5;
    const int wq   = w * 32;

    const size_t qkbase = (size_t)bh * SEQ * HDIM;
    const size_t vbase  = (size_t)h * HDIM * MROWS + (size_t)b * SEQ;

    const int src_row  = tid >> 3, src_ch = tid & 7;
    const int src_gch  = src_ch ^ (src_row & 7);
    const int src_row2 = (tid + 256) >> 3;
    const int src_gch2 = src_ch ^ (src_row2 & 7);
    const int loff1 = src_row  * 64 + src_ch * 8;
    const int loff2 = src_row2 * 64 + src_ch * 8;

    {   // Q (16KB) -> Vb[1..2] (free until iter0's prefetch, consumed before that)
        bf16* Qst = Vb + 4096;
        #pragma unroll
        for (int i = 0; i < 4; ++i) {
            int c = tid + i * 256;
            int row = c >> 3, ch = c & 7;
            int gch = ch ^ (row & 7);
            gload_lds16(Q + qkbase + (size_t)(q0 + row) * HDIM + gch * 8, Qst + row * 64 + ch * 8);
        }
    }

    const bf16* kp1 = Kd + qkbase + (size_t)src_row  * HDIM + src_gch  * 8;
    const bf16* kp2 = Kd + qkbase + (size_t)src_row2 * HDIM + src_gch2 * 8;
    const bf16* vp1 = Vt + vbase  + (size_t)src_row  * MROWS + src_gch  * 8;
    const bf16* vp2 = Vt + vbase  + (size_t)src_row2 * MROWS + src_gch2 * 8;
    const ptrdiff_t kstep = 64 * HDIM, vstep = 64;

    gload_lds16(kp1, Kb + loff1); gload_lds16(kp2, Kb + loff2);
    gload_lds16(vp1, Vb + loff1); gload_lds16(vp2, Vb + loff2);
    __syncthreads();

    bf16x8_t qf[4];
    {
        const bf16* Qst = Vb + 4096;
        int row = wq + l31;
        #pragma unroll
        for (int g = 0; g < 4; ++g) {
            int ch = (2 * g + hw) ^ (row & 7);
            qf[g] = *reinterpret_cast<const bf16x8_t*>(&Qst[row * 64 + ch * 8]);
        }
    }
    __syncthreads();

    f32x16_t oacc[2] = {};
    f32x16_t rsacc  = {};
    bf16x8_t pk[4];
    bf16x8_t ones8;
    #pragma unroll
    for (int i = 0; i < 8; ++i) ones8[i] = (bf16)1.0f;

    int vprev = 2, vcur = 0, vnext = 1;

    for (int it = 0; it < SEQ / 64; ++it) {
        if (it + 1 < SEQ / 64) {
            const ptrdiff_t g = (ptrdiff_t)(it + 1);
            bf16* kd = Kb + ((it + 1) & 1) * 4096;
            bf16* vd = Vb + vnext * 4096;
            gload_lds16(kp1 + g * kstep, kd + loff1); gload_lds16(kp2 + g * kstep, kd + loff2);
            gload_lds16(vp1 + g * vstep, vd + loff1); gload_lds16(vp2 + g * vstep, vd + loff2);
        }

        const bf16* Ks = Kb + (it & 1) * 4096;

        f32x16_t sacc[2] = {};
        __builtin_amdgcn_s_setprio(1);
        #pragma unroll
        for (int kc = 0; kc < 2; ++kc) {
            int row = kc * 32 + l31;
            #pragma unroll
            for (int g = 0; g < 4; ++g) {
                int ch = (2 * g + hw) ^ (row & 7);
                bf16x8_t af = *reinterpret_cast<const bf16x8_t*>(&Ks[row * 64 + ch * 8]);
                sacc[kc] = __builtin_amdgcn_mfma_f32_32x32x16_bf16(af, qf[g], sacc[kc], 0, 0, 0);
            }
        }

        if (it > 0) {   // PV(t-1) + rsacc(t-1): same MFMA cluster as QK(t)
            const bf16* Vs = Vb + vprev * 4096;
            #pragma unroll
            for (int dc = 0; dc < 2; ++dc) {
                int row = dc * 32 + l31;
                #pragma unroll
                for (int kg = 0; kg < 4; ++kg) {
                    int myc = (2 * kg + hw) ^ (row & 7);
                    bf16x8_t bb = *reinterpret_cast<const bf16x8_t*>(&Vs[row * 64 + myc * 8]);
                    oacc[dc] = __builtin_amdgcn_mfma_f32_32x32x16_bf16(pk[kg], bb, oacc[dc], 0, 0, 0);
                }
            }
            #pragma unroll
            for (int kg = 0; kg < 4; ++kg)
                rsacc = __builtin_amdgcn_mfma_f32_32x32x16_bf16(pk[kg], ones8, rsacc, 0, 0, 0);
        }
        __builtin_amdgcn_s_setprio(0);

        #pragma unroll
        for (int kg = 0; kg < 4; ++kg) {
            #pragma unroll
            for (int j = 0; j < 8; ++j)
                pk[kg][j] = (bf16)__builtin_amdgcn_exp2f(sacc[kg >> 1][(kg & 1) * 8 + j]);
        }

        __syncthreads();
        int tmp = vprev; vprev = vcur; vcur = vnext; vnext = tmp;
    }

    {   // epilogue: PV(last) + rsacc(last)
        const bf16* Vs = Vb + vprev * 4096;
        #pragma unroll
        for (int dc = 0; dc < 2; ++dc) {
            int row = dc * 32 + l31;
            #pragma unroll
            for (int kg = 0; kg < 4; ++kg) {
                int myc = (2 * kg + hw) ^ (row & 7);
                bf16x8_t bb = *reinterpret_cast<const bf16x8_t*>(&Vs[row * 64 + myc * 8]);
                oacc[dc] = __builtin_amdgcn_mfma_f32_32x32x16_bf16(pk[kg], bb, oacc[dc], 0, 0, 0);
            }
        }
        #pragma unroll
        for (int kg = 0; kg < 4; ++kg)
            rsacc = __builtin_amdgcn_mfma_f32_32x32x16_bf16(pk[kg], ones8, rsacc, 0, 0, 0);
    }

    float inv[16];
    #pragma unroll
    for (int r = 0; r < 16; ++r)
        inv[r] = 1.0f / rsacc[r];
    #pragma unroll
    for (int dc = 0; dc < 2; ++dc) {
        int d = dc * 32 + l31;
        #pragma unroll
        for (int r = 0; r < 16; ++r) {
            int q = q0 + wq + (r & 3) + 8 * (r >> 2) + 4 * hw;
            Ab[((size_t)b * SEQ + q) * DIM + h * HDIM + d] = (bf16)(oacc[dc][r] * inv[r]);
        }
    }
}

extern "C" void kernel_launch(void* const* d_in, const int* in_sizes, int n_in,
                              void* d_out, int out_size, void* d_ws, size_t ws_size,
                              hipStream_t stream) {
    (void)in_sizes; (void)n_in; (void)out_size; (void)ws_size;
    const float* x  = (const float*)d_in[0];
    const float* Wq = (const float*)d_in[1];
    const float* Wk = (const float*)d_in[2];
    const float* Wv = (const float*)d_in[3];
    const float* Wp = (const float*)d_in[4];
    const float* bp = (const float*)d_in[5];
    float* out = (float*)d_out;

    char* ws = (char*)d_ws;
    size_t off = 0;
    auto alloc = [&](size_t bytes) {
        void* p = ws + off;
        off += (bytes + 255) & ~(size_t)255;
        return p;
    };
    const size_t big = (size_t)MROWS * DIM * sizeof(bf16);
    const size_t wsz = (size_t)DIM * DIM * sizeof(bf16);
    bf16* Xb  = (bf16*)alloc(big);
    bf16* Qb  = (bf16*)alloc(big);
    bf16* Kb  = (bf16*)alloc(big);
    bf16* Vtb = (bf16*)alloc(big);
    bf16* Wqb = (bf16*)alloc(wsz);
    bf16* Wkb = (bf16*)alloc(wsz);
    bf16* Wvb = (bf16*)alloc(wsz);
    bf16* Wpb = (bf16*)alloc(wsz);
    bf16* Ab  = Xb;   // Xb dead after projections

    const int x4 = MROWS * DIM / 4;
    cast_bf16_kernel<<<(x4 + 255) / 256, 256, 0, stream>>>(x, Xb, x4);
    const int w4 = DIM * DIM / 4;
    cast_w4_kernel<<<dim3((w4 + 255) / 256, 4), 256, 0, stream>>>(
        Wq, Wk, Wv, Wp, Wqb, Wkb, Wvb, Wpb, w4);

    qkvv_gemm<<<dim3(DIM / 128, MROWS / 128, 3), 256, 0, stream>>>(
        Xb, Wqb, Wkb, Wvb, Qb, Kb, Vtb);

    attn_kernel<<<dim3(SEQ / 128, BATCH * HEADS), 256, 0, stream>>>(Qb, Kb, Vtb, Ab);

    out_gemm<<<dim3(DIM / 128, MROWS / 64), 256, 0, stream>>>(Ab, Wpb, bp, out);
}